// Round 1
// baseline (7829.967 us; speedup 1.0000x reference)
//
#include <hip/hip_runtime.h>

#define NN 100000
#define NE 800000
#define NL 200000
#define HEADS 4

// ---------------- GEMM: C[r, j] = act(sum_k A[r,k]*B[k,j] + bias[j]) -------
// A is [n_rows, K] row-major (lda == K), B is [K, ncols] row-major.
// Block handles RPB rows with TPB threads; A rows staged in LDS.
template<int K, int TPB, int RPB, bool RELU, bool BIAS>
__launch_bounds__(TPB)
__global__ void gemm_rows(const float* __restrict__ A, const float* __restrict__ B,
                          const float* __restrict__ bias, float* __restrict__ C,
                          int n_rows, int ncols) {
    __shared__ float As[RPB][K];
    const int row0 = blockIdx.x * RPB;
    for (int i = threadIdx.x; i < RPB * K; i += TPB) {
        int r = i / K, k = i % K;
        int gr = row0 + r;
        As[r][k] = (gr < n_rows) ? A[(size_t)gr * K + k] : 0.f;
    }
    __syncthreads();
    const int cpr = TPB / RPB;              // threads per row
    const int r   = threadIdx.x / cpr;
    const int j0  = threadIdx.x % cpr;
    const int gr  = row0 + r;
    if (gr >= n_rows) return;
    for (int j = j0; j < ncols; j += cpr) {
        float s = BIAS ? bias[j] : 0.f;
        #pragma unroll
        for (int k = 0; k < K; ++k) s += As[r][k] * B[k * ncols + j];
        if (RELU) s = fmaxf(s, 0.f);
        C[(size_t)gr * ncols + j] = s;
    }
}

// ---------------- per-(node,head) attention logits --------------------------
template<int C>
__global__ void calc_alpha(const float* __restrict__ h, const float* __restrict__ a_src,
                           const float* __restrict__ a_dst, float* __restrict__ as_out,
                           float* __restrict__ ad_out) {
    int i = blockIdx.x * blockDim.x + threadIdx.x;   // n*HEADS + hd
    if (i >= NN * HEADS) return;
    int n = i / HEADS, hd = i % HEADS;
    const float* hp  = h + (size_t)n * HEADS * C + hd * C;
    const float* asp = a_src + hd * C;
    const float* adp = a_dst + hd * C;
    float s1 = 0.f, s2 = 0.f;
    #pragma unroll 8
    for (int c = 0; c < C; ++c) { float v = hp[c]; s1 += v * asp[c]; s2 += v * adp[c]; }
    as_out[i] = s1; ad_out[i] = s2;
}

__device__ __forceinline__ float lrelu02(float v) { return v > 0.f ? v : 0.2f * v; }

// ---------------- softmax denominator per (dst, head) -----------------------
__global__ void edge_denom(const int* __restrict__ src, const int* __restrict__ dst,
                           const float* __restrict__ as_, const float* __restrict__ ad_,
                           float* __restrict__ den) {
    int i = blockIdx.x * blockDim.x + threadIdx.x;   // e*HEADS + hd
    if (i >= NE * HEADS) return;
    int e = i / HEADS, hd = i % HEADS;
    int s = src[e], d = dst[e];
    float v = lrelu02(as_[s * HEADS + hd] + ad_[d * HEADS + hd]);
    atomicAdd(&den[d * HEADS + hd], __expf(v));
}

// ---------------- weighted aggregation, heads folded ------------------------
// agg[d, c] += sum_h alpha[e,h] * h[s, h*C + c]   (mean over heads applied later)
template<int C>
__global__ void edge_agg(const int* __restrict__ src, const int* __restrict__ dst,
                         const float* __restrict__ as_, const float* __restrict__ ad_,
                         const float* __restrict__ den, const float* __restrict__ h,
                         float* __restrict__ agg) {
    int tid = blockIdx.x * blockDim.x + threadIdx.x;
    int e = tid / C, c = tid % C;
    if (e >= NE) return;
    int s = src[e], d = dst[e];
    float w[HEADS];
    #pragma unroll
    for (int hd = 0; hd < HEADS; ++hd) {
        float v = lrelu02(as_[s * HEADS + hd] + ad_[d * HEADS + hd]);
        w[hd] = __expf(v) / (den[d * HEADS + hd] + 1e-16f);
    }
    float sum = 0.f;
    #pragma unroll
    for (int hd = 0; hd < HEADS; ++hd)
        sum += w[hd] * h[(size_t)s * HEADS * C + hd * C + c];
    atomicAdd(&agg[(size_t)d * C + c], sum);
}

// ---------------- mean over heads + bias + relu ------------------------------
template<int C>
__global__ void finalize(const float* __restrict__ agg, const float* __restrict__ bias,
                         float* __restrict__ out) {
    int i = blockIdx.x * blockDim.x + threadIdx.x;   // n*C + c
    if (i >= NN * C) return;
    out[i] = fmaxf(agg[i] * 0.25f + bias[i % C], 0.f);
}

// ---------------- link decoder ----------------------------------------------
__global__ void link_kernel(const int* __restrict__ lsrc, const int* __restrict__ ldst,
                            const float* __restrict__ z, float* __restrict__ out) {
    int e = blockIdx.x * blockDim.x + threadIdx.x;
    if (e >= NL) return;
    const float4* zs = (const float4*)(z + (size_t)lsrc[e] * 32);
    const float4* zd = (const float4*)(z + (size_t)ldst[e] * 32);
    float sum = 0.f;
    #pragma unroll
    for (int i = 0; i < 8; ++i) {
        float4 a = zs[i], b = zd[i];
        sum += a.x * b.x + a.y * b.y + a.z * b.z + a.w * b.w;
    }
    out[e] = sum;
}

extern "C" void kernel_launch(void* const* d_in, const int* in_sizes, int n_in,
                              void* d_out, int out_size, void* d_ws, size_t ws_size,
                              hipStream_t stream) {
    const float* x     = (const float*)d_in[0];
    const int*   ei    = (const int*)d_in[1];
    const int*   eli   = (const int*)d_in[2];
    const float* W0    = (const float*)d_in[3];
    const float* as0   = (const float*)d_in[4];
    const float* ad0   = (const float*)d_in[5];
    const float* b0    = (const float*)d_in[6];
    const float* W1    = (const float*)d_in[7];
    const float* as1   = (const float*)d_in[8];
    const float* ad1   = (const float*)d_in[9];
    const float* b1    = (const float*)d_in[10];
    const float* lin_w = (const float*)d_in[11];
    const float* lin_b = (const float*)d_in[12];
    const float* d1_w  = (const float*)d_in[13];
    const float* d1_b  = (const float*)d_in[14];
    const float* d2_w  = (const float*)d_in[15];
    const float* d2_b  = (const float*)d_in[16];
    const float* d3_w  = (const float*)d_in[17];
    const float* d3_b  = (const float*)d_in[18];
    const float* d4_w  = (const float*)d_in[19];
    const float* d4_b  = (const float*)d_in[20];

    const int* src = ei;            // edge_index[0]
    const int* dst = ei + NE;       // edge_index[1]
    const int* ls  = eli;
    const int* ld  = eli + NL;

    float* ws = (float*)d_ws;
    // layout (floats): h [N*256] | agg [N*64] | out0/out1 [N*64] | as [N*4] | ad [N*4] | den [N*4]
    float* h_buf = ws;
    float* agg   = ws + (size_t)NN * 256;
    float* outb  = ws + (size_t)NN * 320;
    float* asb   = ws + (size_t)NN * 384;
    float* adb   = ws + (size_t)NN * 388;
    float* den   = ws + (size_t)NN * 392;
    // decoder intermediates reuse the h region
    float* z  = h_buf;                       // [N,32]
    float* e1 = h_buf + (size_t)NN * 32;     // [N,32]
    float* e2 = h_buf + (size_t)NN * 64;     // [N,64]
    float* e3 = h_buf + (size_t)NN * 128;    // [N,96]

    float* link_out = (float*)d_out;
    float* expr_out = (float*)d_out + NL;

    // ---------------- Layer 0 (C=64 per head) ----------------
    gemm_rows<64, 256, 4, false, false><<<NN / 4, 256, 0, stream>>>(x, W0, nullptr, h_buf, NN, 256);
    calc_alpha<64><<<(NN * HEADS + 255) / 256, 256, 0, stream>>>(h_buf, as0, ad0, asb, adb);
    hipMemsetAsync(den, 0, (size_t)NN * HEADS * 4, stream);
    edge_denom<<<(NE * HEADS + 255) / 256, 256, 0, stream>>>(src, dst, asb, adb, den);
    hipMemsetAsync(agg, 0, (size_t)NN * 64 * 4, stream);
    edge_agg<64><<<(size_t)(NE * 64) / 256, 256, 0, stream>>>(src, dst, asb, adb, den, h_buf, agg);
    finalize<64><<<(NN * 64) / 256, 256, 0, stream>>>(agg, b0, outb);

    // ---------------- Layer 1 (C=32 per head) ----------------
    gemm_rows<64, 256, 4, false, false><<<NN / 4, 256, 0, stream>>>(outb, W1, nullptr, h_buf, NN, 128);
    calc_alpha<32><<<(NN * HEADS + 255) / 256, 256, 0, stream>>>(h_buf, as1, ad1, asb, adb);
    hipMemsetAsync(den, 0, (size_t)NN * HEADS * 4, stream);
    edge_denom<<<(NE * HEADS + 255) / 256, 256, 0, stream>>>(src, dst, asb, adb, den);
    hipMemsetAsync(agg, 0, (size_t)NN * 32 * 4, stream);
    edge_agg<32><<<(size_t)(NE * 32) / 256, 256, 0, stream>>>(src, dst, asb, adb, den, h_buf, agg);
    finalize<32><<<(NN * 32) / 256, 256, 0, stream>>>(agg, b1, outb);

    // ---------------- lin: z = out1 @ lin_w + lin_b ----------------
    gemm_rows<32, 256, 8, false, true><<<NN / 8, 256, 0, stream>>>(outb, lin_w, lin_b, z, NN, 32);

    // ---------------- link decoder ----------------
    link_kernel<<<(NL + 255) / 256, 256, 0, stream>>>(ls, ld, z, link_out);

    // ---------------- expression decoder ----------------
    gemm_rows<32, 256, 8, true, true><<<NN / 8, 256, 0, stream>>>(z,  d1_w, d1_b, e1, NN, 32);
    gemm_rows<32, 256, 8, true, true><<<NN / 8, 256, 0, stream>>>(e1, d2_w, d2_b, e2, NN, 64);
    gemm_rows<64, 256, 4, true, true><<<NN / 4, 256, 0, stream>>>(e2, d3_w, d3_b, e3, NN, 96);
    gemm_rows<96, 256, 2, false, true><<<NN / 2, 256, 0, stream>>>(e3, d4_w, d4_b, expr_out, NN, 500);
}